// Round 4
// baseline (195.738 us; speedup 1.0000x reference)
//
#include <hip/hip_runtime.h>

// PINN fused: u, du/dx0, d2u/dx0^2 of tanh-MLP (2->256->256->256->1), fp32 in/out.
// Round 10: attack VALU<->MFMA serialization (round-9 post-mortem: occupancy
// 21->40% changed nothing; VALU 157K cyc + MFMA 119K cyc == 276K ~= measured
// runtime -> phases SUM. Blocks convoy, so cross-block overlap never happens).
//   - two 16-sample sub-tiles per block, phase-offset by one stage; each slot
//     statically interleaves one tile's 12-MFMA groups with the other tile's
//     tanh/pack VALU chunks IN THE SAME WAVE's instruction stream:
//       slot1: L1(A)            slot4: M3(A) || E2(B)
//       slot2: M2(A) || L1(B)   slot5: M3(B) || E3(A)
//       slot3: M2(B) || E2(A)   slot6: E3(B)
//   - LDS 2x24KB tiles + psum = 49.9KB -> 2 blocks/CU (overlap is intra-wave,
//     occupancy no longer load-bearing).
//   - s_setprio(1) around MFMA clusters kept.

#define HID 256
#define TM  32

typedef _Float16 half8 __attribute__((ext_vector_type(8)));
typedef _Float16 half4 __attribute__((ext_vector_type(4)));
typedef float    f32x4 __attribute__((ext_vector_type(4)));

#define MFMA16 __builtin_amdgcn_mfma_f32_16x16x32_f16

__device__ __forceinline__ float fast_tanh(float z) {
    // tanh(z) = 1 - 2/(exp(2z)+1); saturates correctly at +-inf
    const float e = __expf(2.0f * z);
#if __has_builtin(__builtin_amdgcn_rcpf)
    const float r = __builtin_amdgcn_rcpf(e + 1.0f);
#else
    const float r = 1.0f / (e + 1.0f);
#endif
    return fmaf(-2.0f, r, 1.0f);
}

// Pack W2/W3 (fp32 [256][256], row=k, col=n) into MFMA A-fragment order for W^T,
// fp16 (hi) only.  Layout: elem = ((kc*16 + strip)*64 + lane)*8 + j  (strip =
// wave*4 + nt), so a wave's 4 strips per kc are imm-offset addressable.
// frag value (kc, strip, lane, j) = W[kc*32 + (lane>>4)*8 + j][strip*16 + (lane&15)]
// ws layout (f16 elems): W2 @ 0, W3 @ 65536.  (256KB total)
__global__ __launch_bounds__(256) void prep_w(const float* __restrict__ W2,
                                              const float* __restrict__ W3,
                                              _Float16* __restrict__ wsf) {
    const int t = blockIdx.x * 256 + threadIdx.x;     // 0..16383
    const float* __restrict__ W = (t >> 13) ? W3 : W2;
    _Float16* dst = wsf + (size_t)(t >> 13) * 65536;
    const int r     = t & 8191;
    const int kc    = r >> 10;          // 0..7
    const int strip = (r >> 6) & 15;    // 0..15
    const int lane  = r & 63;
    const int row   = kc * 32 + ((lane >> 4) << 3);
    const int col   = strip * 16 + (lane & 15);
    half8 vh;
    #pragma unroll
    for (int j = 0; j < 8; ++j)
        vh[j] = (_Float16)W[(size_t)(row + j) * HID + col];
    *(half8*)&dst[(size_t)r * 8] = vh;
}

// ---- phase building blocks (macros so all indices stay compile-time) ----

// one kc step of a 16-sample sub-tile: 3 A-frag LDS reads + 4 W-frag loads + 12 MFMA
#define MSTEP(Abase, Wl, acc, kc) do {                                          \
    const _Float16* __restrict__ Ap_ = (Abase) + ml * 256                       \
                                     + (((((kc) << 2) | hi) ^ rk) << 3);        \
    const half8 a0_ = *(const half8*)&Ap_[0];                                   \
    const half8 a1_ = *(const half8*)&Ap_[4096];                                \
    const half8 a2_ = *(const half8*)&Ap_[8192];                                \
    const _Float16* __restrict__ Wk_ = (Wl) + ((kc) << 13);                     \
    const half8 w0_ = *(const half8*)&Wk_[0];                                   \
    const half8 w1_ = *(const half8*)&Wk_[512];                                 \
    const half8 w2_ = *(const half8*)&Wk_[1024];                                \
    const half8 w3_ = *(const half8*)&Wk_[1536];                                \
    __builtin_amdgcn_s_setprio(1);                                              \
    acc[0][0] = MFMA16(w0_, a0_, acc[0][0], 0, 0, 0);                           \
    acc[1][0] = MFMA16(w0_, a1_, acc[1][0], 0, 0, 0);                           \
    acc[2][0] = MFMA16(w0_, a2_, acc[2][0], 0, 0, 0);                           \
    acc[0][1] = MFMA16(w1_, a0_, acc[0][1], 0, 0, 0);                           \
    acc[1][1] = MFMA16(w1_, a1_, acc[1][1], 0, 0, 0);                           \
    acc[2][1] = MFMA16(w1_, a2_, acc[2][1], 0, 0, 0);                           \
    acc[0][2] = MFMA16(w2_, a0_, acc[0][2], 0, 0, 0);                           \
    acc[1][2] = MFMA16(w2_, a1_, acc[1][2], 0, 0, 0);                           \
    acc[2][2] = MFMA16(w2_, a2_, acc[2][2], 0, 0, 0);                           \
    acc[0][3] = MFMA16(w3_, a0_, acc[0][3], 0, 0, 0);                           \
    acc[1][3] = MFMA16(w3_, a1_, acc[1][3], 0, 0, 0);                           \
    acc[2][3] = MFMA16(w3_, a2_, acc[2][3], 0, 0, 0);                           \
    __builtin_amdgcn_s_setprio(0);                                              \
} while (0)

// layer-1 for 4 units (chunk c=0..3) of sample mL, swizzled write into dst tile
#define L1_CHUNK(dst, xv, c) do {                                               \
    const int n0_ = k0 + ((c) << 2);                                            \
    const f32x4 w0_ = *(const f32x4*)&W1[n0_];                                  \
    const f32x4 w1_ = *(const f32x4*)&W1[HID + n0_];                            \
    const f32x4 bb_ = *(const f32x4*)&b1[n0_];                                  \
    half4 h0_, h1_, h2_;                                                        \
    _Pragma("unroll")                                                           \
    for (int r = 0; r < 4; ++r) {                                               \
        const float z_  = fmaf((xv).x, w0_[r], fmaf((xv).y, w1_[r], bb_[r]));   \
        const float a_  = fast_tanh(z_);                                        \
        const float sN_ = 1.0f - a_ * a_;                                       \
        const float ad_  = sN_ * w0_[r];                                        \
        const float add_ = -2.0f * a_ * ad_ * w0_[r];                           \
        h0_[r] = (_Float16)a_; h1_[r] = (_Float16)ad_; h2_[r] = (_Float16)add_; \
    }                                                                           \
    const int go_ = (((n0_ >> 3) ^ (mL & 7)) << 3) + (n0_ & 7);                 \
    _Float16* dp_ = &(dst)[mL * 256 + go_];                                     \
    *(half4*)&dp_[0]    = h0_;                                                  \
    *(half4*)&dp_[4096] = h1_;                                                  \
    *(half4*)&dp_[8192] = h2_;                                                  \
} while (0)

// layer-2 epilogue for one nt strip (4 units): tanh chain + swizzled LDS write
#define E2_CHUNK(dst, acc, nt) do {                                             \
    const int ub_ = (wave << 6) + ((nt) << 4) + u4;                             \
    const f32x4 bb_ = *(const f32x4*)&b2[ub_];                                  \
    const int gs_ = (((ub_ >> 3) ^ rk) << 3) + (u4 & 4);                        \
    half4 h0_, h1_, h2_;                                                        \
    _Pragma("unroll")                                                           \
    for (int r = 0; r < 4; ++r) {                                               \
        const float z_   = acc[0][nt][r] + bb_[r];                              \
        const float a_   = fast_tanh(z_);                                       \
        const float sN_  = 1.0f - a_ * a_;                                      \
        const float zd_  = acc[1][nt][r];                                       \
        const float zdd_ = acc[2][nt][r];                                       \
        const float ad_  = sN_ * zd_;                                           \
        const float add_ = fmaf(sN_, zdd_, -2.0f * a_ * ad_ * zd_);             \
        h0_[r] = (_Float16)a_; h1_[r] = (_Float16)ad_; h2_[r] = (_Float16)add_; \
    }                                                                           \
    _Float16* dp_ = &(dst)[ml * 256 + gs_];                                     \
    *(half4*)&dp_[0]    = h0_;                                                  \
    *(half4*)&dp_[4096] = h1_;                                                  \
    *(half4*)&dp_[8192] = h2_;                                                  \
} while (0)

// layer-3 epilogue for one nt strip fused with W4 dot (registers only)
#define E3_CHUNK(acc, pd, nt) do {                                              \
    const int ub_ = (wave << 6) + ((nt) << 4) + u4;                             \
    const f32x4 bb_ = *(const f32x4*)&b3[ub_];                                  \
    const f32x4 w4_ = *(const f32x4*)&W4[ub_];                                  \
    _Pragma("unroll")                                                           \
    for (int r = 0; r < 4; ++r) {                                               \
        const float z_   = acc[0][nt][r] + bb_[r];                              \
        const float a_   = fast_tanh(z_);                                       \
        const float sN_  = 1.0f - a_ * a_;                                      \
        const float zd_  = acc[1][nt][r];                                       \
        const float zdd_ = acc[2][nt][r];                                       \
        const float ad_  = sN_ * zd_;                                           \
        const float add_ = fmaf(sN_, zdd_, -2.0f * a_ * ad_ * zd_);             \
        pd[0] = fmaf(a_,   w4_[r], pd[0]);                                      \
        pd[1] = fmaf(ad_,  w4_[r], pd[1]);                                      \
        pd[2] = fmaf(add_, w4_[r], pd[2]);                                      \
    }                                                                           \
} while (0)

#define ZERO_ACC(acc) do {                                                      \
    _Pragma("unroll")                                                           \
    for (int s_ = 0; s_ < 3; ++s_)                                              \
        _Pragma("unroll")                                                       \
        for (int n_ = 0; n_ < 4; ++n_)                                          \
            acc[s_][n_] = (f32x4){0.f, 0.f, 0.f, 0.f};                          \
} while (0)

__global__ __launch_bounds__(256, 2) void pinn_mfma(
    const float* __restrict__ x,
    const float* __restrict__ W1, const float* __restrict__ b1,
    const float* __restrict__ b2, const float* __restrict__ b3,
    const float* __restrict__ W4, const float* __restrict__ b4,
    const _Float16* __restrict__ wsf,
    float* __restrict__ out, int B)
{
    // Two sub-tile A-buffers: 3 streams x 16 rows x 256 elems fp16 each,
    // 16B-granule XOR swizzle: elem(s,row,e) at s*4096 + row*256
    //                                         + (((e>>3) ^ (row&7))<<3) + (e&7)
    __shared__ __align__(16) _Float16 AhiA[3 * 16 * 256];   // 24 KB
    __shared__ __align__(16) _Float16 AhiB[3 * 16 * 256];   // 24 KB
    __shared__ float psum[2][4][3][16];                     // 1.5 KB

    const int tid  = threadIdx.x;
    const int s0   = blockIdx.x * TM;
    const int lane = tid & 63;
    const int wave = tid >> 6;          // 0..3

    // L1 mapping: thread owns sample mL (tile-local), 16 units k0..k0+15
    const int mL = tid & 15;
    const int k0 = (tid >> 4) << 4;
    // MFMA / epilogue mapping
    const int ml = lane & 15;            // B/D col = sample
    const int hi = lane >> 4;            // 0..3
    const int rk = ml & 7;               // swizzle key
    const int u4 = hi << 2;

    const float2 xA = *(const float2*)&x[(size_t)(s0 + mL) * 2];
    const float2 xB = *(const float2*)&x[(size_t)(s0 + 16 + mL) * 2];

    const _Float16* __restrict__ W2l = wsf + (wave << 11) + (lane << 3);
    const _Float16* __restrict__ W3l = W2l + 65536;

    f32x4 accA[3][4], accB[3][4];

    // ---- slot 1: L1(A) ----
    L1_CHUNK(AhiA, xA, 0); L1_CHUNK(AhiA, xA, 1);
    L1_CHUNK(AhiA, xA, 2); L1_CHUNK(AhiA, xA, 3);
    __syncthreads();

    // ---- slot 2: M2(A) || L1(B) ----
    ZERO_ACC(accA);
    MSTEP(AhiA, W2l, accA, 0); L1_CHUNK(AhiB, xB, 0); MSTEP(AhiA, W2l, accA, 1);
    MSTEP(AhiA, W2l, accA, 2); L1_CHUNK(AhiB, xB, 1); MSTEP(AhiA, W2l, accA, 3);
    MSTEP(AhiA, W2l, accA, 4); L1_CHUNK(AhiB, xB, 2); MSTEP(AhiA, W2l, accA, 5);
    MSTEP(AhiA, W2l, accA, 6); L1_CHUNK(AhiB, xB, 3); MSTEP(AhiA, W2l, accA, 7);
    __syncthreads();   // A-reads done (E2 will overwrite AhiA); AhiB visible

    // ---- slot 3: M2(B) || E2(A) ----
    ZERO_ACC(accB);
    MSTEP(AhiB, W2l, accB, 0); E2_CHUNK(AhiA, accA, 0); MSTEP(AhiB, W2l, accB, 1);
    MSTEP(AhiB, W2l, accB, 2); E2_CHUNK(AhiA, accA, 1); MSTEP(AhiB, W2l, accB, 3);
    MSTEP(AhiB, W2l, accB, 4); E2_CHUNK(AhiA, accA, 2); MSTEP(AhiB, W2l, accB, 5);
    MSTEP(AhiB, W2l, accB, 6); E2_CHUNK(AhiA, accA, 3); MSTEP(AhiB, W2l, accB, 7);
    __syncthreads();   // B-reads done; new AhiA visible

    // ---- slot 4: M3(A) || E2(B) ----
    ZERO_ACC(accA);
    MSTEP(AhiA, W3l, accA, 0); E2_CHUNK(AhiB, accB, 0); MSTEP(AhiA, W3l, accA, 1);
    MSTEP(AhiA, W3l, accA, 2); E2_CHUNK(AhiB, accB, 1); MSTEP(AhiA, W3l, accA, 3);
    MSTEP(AhiA, W3l, accA, 4); E2_CHUNK(AhiB, accB, 2); MSTEP(AhiA, W3l, accA, 5);
    MSTEP(AhiA, W3l, accA, 6); E2_CHUNK(AhiB, accB, 3); MSTEP(AhiA, W3l, accA, 7);
    __syncthreads();   // new AhiB visible

    // ---- slot 5: M3(B) || E3(A) ----
    ZERO_ACC(accB);
    float pdA[3] = {0.f, 0.f, 0.f};
    MSTEP(AhiB, W3l, accB, 0); E3_CHUNK(accA, pdA, 0); MSTEP(AhiB, W3l, accB, 1);
    MSTEP(AhiB, W3l, accB, 2); E3_CHUNK(accA, pdA, 1); MSTEP(AhiB, W3l, accB, 3);
    MSTEP(AhiB, W3l, accB, 4); E3_CHUNK(accA, pdA, 2); MSTEP(AhiB, W3l, accB, 5);
    MSTEP(AhiB, W3l, accB, 6); E3_CHUNK(accA, pdA, 3); MSTEP(AhiB, W3l, accB, 7);
    // finish E3(A): butterfly over lanes {ml, ml+16, ml+32, ml+48}
    #pragma unroll
    for (int s = 0; s < 3; ++s) {
        pdA[s] += __shfl_xor(pdA[s], 16, 64);
        pdA[s] += __shfl_xor(pdA[s], 32, 64);
    }
    if (lane < 16) {
        #pragma unroll
        for (int s = 0; s < 3; ++s) psum[0][wave][s][lane] = pdA[s];
    }

    // ---- slot 6: E3(B) ----
    float pdB[3] = {0.f, 0.f, 0.f};
    E3_CHUNK(accB, pdB, 0); E3_CHUNK(accB, pdB, 1);
    E3_CHUNK(accB, pdB, 2); E3_CHUNK(accB, pdB, 3);
    #pragma unroll
    for (int s = 0; s < 3; ++s) {
        pdB[s] += __shfl_xor(pdB[s], 16, 64);
        pdB[s] += __shfl_xor(pdB[s], 32, 64);
    }
    if (lane < 16) {
        #pragma unroll
        for (int s = 0; s < 3; ++s) psum[1][wave][s][lane] = pdB[s];
    }
    __syncthreads();

    if (tid < 96) {
        const int s  = tid >> 5;         // 0:u 1:du 2:d2u
        const int m  = tid & 31;         // sample within TM=32
        const int t  = m >> 4;           // sub-tile
        const int mm = m & 15;
        float v = psum[t][0][s][mm] + psum[t][1][s][mm]
                + psum[t][2][s][mm] + psum[t][3][s][mm];
        if (s == 0) v += b4[0];
        out[(size_t)s * B + s0 + m] = v;
    }
}

extern "C" void kernel_launch(void* const* d_in, const int* in_sizes, int n_in,
                              void* d_out, int out_size, void* d_ws, size_t ws_size,
                              hipStream_t stream) {
    const float* x  = (const float*)d_in[0];
    const float* W1 = (const float*)d_in[1];
    const float* b1 = (const float*)d_in[2];
    const float* W2 = (const float*)d_in[3];
    const float* b2 = (const float*)d_in[4];
    const float* W3 = (const float*)d_in[5];
    const float* b3 = (const float*)d_in[6];
    const float* W4 = (const float*)d_in[7];
    const float* b4 = (const float*)d_in[8];
    float* out = (float*)d_out;

    const int B = in_sizes[0] / 2;      // x is (B, 2)

    prep_w<<<64, 256, 0, stream>>>(W2, W3, (_Float16*)d_ws);
    pinn_mfma<<<B / TM, 256, 0, stream>>>(x, W1, b1, b2, b3, W4, b4,
                                          (const _Float16*)d_ws, out, B);
}